// Round 3
// baseline (5549.349 us; speedup 1.0000x reference)
//
#include <hip/hip_runtime.h>
#include <stdint.h>

// ---------------- problem constants ----------------
#define TSTEPS 256
#define KB0  36      // (128+1024)/32 k-blocks, layer 0
#define KB1  64      // (1024+1024)/32 k-blocks, layer 1

// workspace layout (bytes)
#define WPK0_OFF 0ull
#define WPK1_OFF 9437184ull
#define A0_OFF   26214400ull
#define A1_OFF   63963136ull
#define BIAS_OFF 131072000ull
#define FLG_OFF  131104768ull
// total needed: 131,137,536 B

typedef __attribute__((ext_vector_type(8))) short bf16x8;
typedef __attribute__((ext_vector_type(4))) float f32x4;

__device__ __forceinline__ unsigned short f2bf(float x) {
  unsigned int u = __float_as_uint(x);
  u = (u + 0x7FFFu + ((u >> 16) & 1u)) >> 16;
  return (unsigned short)u;
}

// position shuffle inside a 32-k block so each lane's 8 fragment elements
// (k in {4g..4g+3} U {16+4g..16+4g+3}, g = lane>>4) are 16B-contiguous.
__device__ __forceinline__ int kpos(int k) {
  return (((k & 15) >> 2) << 3) + (((k >> 4) & 1) << 2) + (k & 3);
}

__device__ __forceinline__ float sigm(float z) {
  return 1.0f / (1.0f + __expf(-z));
}

// all-256-thread flag wait: each thread polls its own flag line; ballot exit.
__device__ __forceinline__ void spin_wait(unsigned int* p, unsigned int tgt) {
  for (;;) {
    unsigned int v = __hip_atomic_load(p, __ATOMIC_RELAXED, __HIP_MEMORY_SCOPE_AGENT);
    if (__syncthreads_and((int)(v >= tgt))) break;
    __builtin_amdgcn_s_sleep(2);
  }
  (void)__hip_atomic_load(p, __ATOMIC_ACQUIRE, __HIP_MEMORY_SCOPE_AGENT);
}

// ---------------- pre-kernels ----------------
__global__ void k_init(const float* __restrict__ bih0, const float* __restrict__ bhh0,
                       const float* __restrict__ bih1, const float* __restrict__ bhh1,
                       float* __restrict__ bias, unsigned int* __restrict__ flg) {
  int i = blockIdx.x * 256 + threadIdx.x;   // 8192 threads
  flg[i] = 0u;                              // flags0[128*32] + flags1[128*32]
  if (i < 4096) {
    bias[i]        = bih0[i] + bhh0[i];
    bias[4096 + i] = bih1[i] + bhh1[i];
  }
}

// pack [Wih | Whh] (4096 x K) -> fragment-native bf16
__global__ void k_packW(const float* __restrict__ Wih, const float* __restrict__ Whh,
                        const int Kih, const int KB, unsigned short* __restrict__ dst) {
  const int K = KB << 5;
  const int total = K << 12;                 // 4096*K
  int i = blockIdx.x * 256 + threadIdx.x;
  if (i >= total) return;
  int n = i / K, k = i - n * K;
  float w = (k < Kih) ? Wih[n * Kih + k] : Whh[n * 1024 + (k - Kih)];
  int gt = n >> 10, hcol = n & 1023;
  int wgi = hcol >> 3, j = hcol & 7;
  int nt = gt >> 1;
  int l15 = ((gt & 1) << 3) | j;             // ntile0: i|f cols, ntile1: g|o cols
  int kb = k >> 5;
  size_t idx = ((size_t)((wgi * 2 + nt) * KB + kb) << 9) + (l15 << 5) + kpos(k & 31);
  dst[idx] = f2bf(w);
}

// pack x (B,T,V) into A0(t) k=0..127 region for all t
__global__ void k_packX(const float* __restrict__ x, unsigned short* __restrict__ a0) {
  int i = blockIdx.x * 256 + threadIdx.x;    // 2,097,152 threads
  int v = i & 127, t = (i >> 7) & 255, b = i >> 15;
  a0[(size_t)t * 73728 + (size_t)(((v >> 5) << 6) + b) * 32 + kpos(v & 31)] = f2bf(x[i]);
}

// initial h: h[0] -> A0(0) k=128+hc ; h[1] -> A1(0) k=1024+hc
__global__ void k_packH(const float* __restrict__ h,
                        unsigned short* __restrict__ a0, unsigned short* __restrict__ a1) {
  int i = blockIdx.x * 256 + threadIdx.x;    // 131072 threads
  int l = i >> 16, b = (i >> 10) & 63, hc = i & 1023;
  unsigned short v = f2bf(h[i]);
  if (l == 0) {
    int k = 128 + hc;
    a0[(size_t)(((k >> 5) << 6) + b) * 32 + kpos(k & 31)] = v;
  } else {
    int k = 1024 + hc;
    a1[(size_t)(((k >> 5) << 6) + b) * 32 + kpos(k & 31)] = v;
  }
}

// ---------------- main persistent kernel ----------------
template <int LAYER>
__device__ __forceinline__ void run_layer(
    const int wg, const int tid,
    const float* __restrict__ c_in, float* __restrict__ out,
    const unsigned short* __restrict__ W,
    unsigned short* __restrict__ a0, unsigned short* __restrict__ a1,
    const float* __restrict__ bias,
    unsigned int* flags0, unsigned int* flags1,
    float (*red)[64][17], unsigned short* ldsw) {
  constexpr int KB = LAYER ? KB1 : KB0;
  constexpr int KBW = KB / 4;                 // k-blocks per wave (16 / 9)
  constexpr int AELEM = KB * 2048;            // elements per t-buffer

  const int lane = tid & 63, wv = tid >> 6;
  const int l15 = lane & 15, lg = lane >> 4;
  const int aoff = l15 * 32 + lg * 8;         // A fragment offset (global layout)
  const int lbo = lane * 8;                   // B fragment offset (LDS lane-linear)

  const unsigned short* Ard = LAYER ? a1 : a0;

  // ---- stage weight slice into LDS once, lane-linear unit permutation ----
  // global 16B-unit u within a 1KB (nt,kb) block encodes (l15=u>>2, lg=u&3);
  // store at unit lg*16+l15 so ds_read_b128 at lane*16B is conflict-free.
  {
    const unsigned short* Wg = W + (size_t)(wg * 2) * KB * 512;
    for (int i = tid; i < KB * 128; i += 256) {
      int u = i & 63;
      *(bf16x8*)(ldsw + (size_t)((((i >> 6) << 6) | ((u & 3) << 4) | (u >> 2)) * 8)) =
          *(const bf16x8*)(Wg + (size_t)i * 8);
    }
  }

  // gate-math assignment: thread -> (batch row gb, h-col pair hc0, hc0+1)
  const int gb = tid >> 2, gj = (tid & 3) << 1;
  const int hc0 = wg * 8 + gj;
  float cc0 = c_in[LAYER * 65536 + gb * 1024 + hc0];
  float cc1 = c_in[LAYER * 65536 + gb * 1024 + hc0 + 1];
  float bg[4][2];
#pragma unroll
  for (int g = 0; g < 4; ++g) {
    bg[g][0] = bias[LAYER * 4096 + g * 1024 + hc0];
    bg[g][1] = bias[LAYER * 4096 + g * 1024 + hc0 + 1];
  }

  unsigned int* myflag = (LAYER ? flags1 : flags0) + wg * 32;
  __syncthreads();  // ldsw ready

  for (int t = 0; t < TSTEPS; ++t) {
    // ---- cross-WG wait (per-WG flag lines, parallel poll + ballot) ----
    if (LAYER == 0) {
      if (t) spin_wait(flags0 + (tid & 127) * 32, (unsigned int)t);
    } else {
      unsigned int* p;
      unsigned int tgt;
      if (tid < 128) { p = flags0 + tid * 32; tgt = (unsigned int)(t + 1); }
      else           { p = flags1 + (tid - 128) * 32; tgt = (unsigned int)t; }
      spin_wait(p, tgt);
    }

    // ---- GEMM: z = A(t) @ Wslice^T, K split across 4 waves ----
    const unsigned short* Ak = Ard + (size_t)t * AELEM + (size_t)(wv * KBW) * 2048 + aoff;

    // prefetch ALL A fragments for this step into registers (static indices)
    bf16x8 abuf[KBW][4];
#pragma unroll
    for (int kk = 0; kk < KBW; ++kk)
#pragma unroll
      for (int m = 0; m < 4; ++m)
        abuf[kk][m] = *(const bf16x8*)(Ak + kk * 2048 + m * 512);

    f32x4 acc[4][2];
#pragma unroll
    for (int mt = 0; mt < 4; ++mt) {
      acc[mt][0] = (f32x4){0.f, 0.f, 0.f, 0.f};
      acc[mt][1] = (f32x4){0.f, 0.f, 0.f, 0.f};
    }
#pragma unroll
    for (int kk = 0; kk < KBW; ++kk) {
      bf16x8 b0 = *(const bf16x8*)(ldsw + (wv * KBW + kk) * 512 + lbo);
      bf16x8 b1 = *(const bf16x8*)(ldsw + (KB + wv * KBW + kk) * 512 + lbo);
      acc[0][0] = __builtin_amdgcn_mfma_f32_16x16x32_bf16(abuf[kk][0], b0, acc[0][0], 0, 0, 0);
      acc[1][0] = __builtin_amdgcn_mfma_f32_16x16x32_bf16(abuf[kk][1], b0, acc[1][0], 0, 0, 0);
      acc[2][0] = __builtin_amdgcn_mfma_f32_16x16x32_bf16(abuf[kk][2], b0, acc[2][0], 0, 0, 0);
      acc[3][0] = __builtin_amdgcn_mfma_f32_16x16x32_bf16(abuf[kk][3], b0, acc[3][0], 0, 0, 0);
      acc[0][1] = __builtin_amdgcn_mfma_f32_16x16x32_bf16(abuf[kk][0], b1, acc[0][1], 0, 0, 0);
      acc[1][1] = __builtin_amdgcn_mfma_f32_16x16x32_bf16(abuf[kk][1], b1, acc[1][1], 0, 0, 0);
      acc[2][1] = __builtin_amdgcn_mfma_f32_16x16x32_bf16(abuf[kk][2], b1, acc[2][1], 0, 0, 0);
      acc[3][1] = __builtin_amdgcn_mfma_f32_16x16x32_bf16(abuf[kk][3], b1, acc[3][1], 0, 0, 0);
    }

    // ---- cross-wave K reduction via LDS, one ntile per pass + gate z sums ----
    float z[4][2];
#pragma unroll
    for (int g = 0; g < 4; ++g) { z[g][0] = bg[g][0]; z[g][1] = bg[g][1]; }
#pragma unroll
    for (int nt = 0; nt < 2; ++nt) {
      __syncthreads();
#pragma unroll
      for (int mt = 0; mt < 4; ++mt)
#pragma unroll
        for (int r = 0; r < 4; ++r)
          red[wv][mt * 16 + lg * 4 + r][l15] = acc[mt][nt][r];
      __syncthreads();
#pragma unroll
      for (int w = 0; w < 4; ++w)
#pragma unroll
        for (int gl = 0; gl < 2; ++gl) {
          z[nt * 2 + gl][0] += red[w][gb][gl * 8 + gj];
          z[nt * 2 + gl][1] += red[w][gb][gl * 8 + gj + 1];
        }
    }

    // ---- gate math (f32), c kept in registers across all steps ----
    float i0 = sigm(z[0][0]), f0 = sigm(z[1][0]), g0 = tanhf(z[2][0]), o0 = sigm(z[3][0]);
    cc0 = f0 * cc0 + i0 * g0;
    float hv0 = o0 * tanhf(cc0);
    float i1 = sigm(z[0][1]), f1 = sigm(z[1][1]), g1 = tanhf(z[2][1]), o1 = sigm(z[3][1]);
    cc1 = f1 * cc1 + i1 * g1;
    float hv1 = o1 * tanhf(cc1);

    unsigned int hpk = ((unsigned int)f2bf(hv1) << 16) | (unsigned int)f2bf(hv0);

    if (LAYER == 0) {
      {  // h0(t) -> A1(t) first half (k = hc)
        int k = hc0;
        size_t idx = (size_t)t * 131072 + (size_t)(((k >> 5) << 6) + gb) * 32 + kpos(k & 31);
        *(unsigned int*)(a1 + idx) = hpk;
      }
      if (t < TSTEPS - 1) {  // h0(t) -> A0(t+1) (k = 128+hc)
        int k = 128 + hc0;
        size_t idx = (size_t)(t + 1) * 73728 + (size_t)(((k >> 5) << 6) + gb) * 32 + kpos(k & 31);
        *(unsigned int*)(a0 + idx) = hpk;
      }
    } else {
      // outs[b][t][hc] in f32
      *(float2*)(out + ((size_t)gb * 256 + t) * 1024 + hc0) = make_float2(hv0, hv1);
      if (t < TSTEPS - 1) {  // h1(t) -> A1(t+1) second half (k = 1024+hc)
        int k = 1024 + hc0;
        size_t idx = (size_t)(t + 1) * 131072 + (size_t)(((k >> 5) << 6) + gb) * 32 + kpos(k & 31);
        *(unsigned int*)(a1 + idx) = hpk;
      }
    }
    if (t == TSTEPS - 1) {  // final h_f / c_f in f32
      size_t base = 16777216ull + (size_t)LAYER * 65536 + (size_t)gb * 1024 + hc0;
      out[base] = hv0;
      out[base + 1] = hv1;
      out[base + 131072] = cc0;
      out[base + 131072 + 1] = cc1;
    }

    __syncthreads();  // drains all threads' A/out stores before flag release
    if (tid == 0)
      __hip_atomic_store(myflag, (unsigned int)(t + 1), __ATOMIC_RELEASE,
                         __HIP_MEMORY_SCOPE_AGENT);
  }
}

__global__ __launch_bounds__(256, 1) void lstm_main(
    const float* __restrict__ c_in, float* __restrict__ out,
    const unsigned short* __restrict__ wpk0, const unsigned short* __restrict__ wpk1,
    unsigned short* a0, unsigned short* a1,
    const float* __restrict__ bias, unsigned int* flg) {
  __shared__ float red[4][64][17];               // 17,408 B (2-pass reduce)
  __shared__ unsigned short ldsw[KB1 * 1024];    // 131,072 B (weight slice)
  int bid = blockIdx.x, tid = threadIdx.x;
  unsigned int* flags0 = flg;
  unsigned int* flags1 = flg + 4096;
  if (bid < 128)
    run_layer<0>(bid, tid, c_in, out, wpk0, a0, a1, bias, flags0, flags1, red, ldsw);
  else
    run_layer<1>(bid - 128, tid, c_in, out, wpk1, a0, a1, bias, flags0, flags1, red, ldsw);
}

// ---------------- host ----------------
extern "C" void kernel_launch(void* const* d_in, const int* in_sizes, int n_in,
                              void* d_out, int out_size, void* d_ws, size_t ws_size,
                              hipStream_t stream) {
  const float* x    = (const float*)d_in[0];
  const float* h    = (const float*)d_in[1];
  const float* c    = (const float*)d_in[2];
  const float* Wih0 = (const float*)d_in[3];
  const float* Whh0 = (const float*)d_in[4];
  const float* bih0 = (const float*)d_in[5];
  const float* bhh0 = (const float*)d_in[6];
  const float* Wih1 = (const float*)d_in[7];
  const float* Whh1 = (const float*)d_in[8];
  const float* bih1 = (const float*)d_in[9];
  const float* bhh1 = (const float*)d_in[10];

  char* ws = (char*)d_ws;
  unsigned short* wpk0 = (unsigned short*)(ws + WPK0_OFF);
  unsigned short* wpk1 = (unsigned short*)(ws + WPK1_OFF);
  unsigned short* a0   = (unsigned short*)(ws + A0_OFF);
  unsigned short* a1   = (unsigned short*)(ws + A1_OFF);
  float* bias          = (float*)(ws + BIAS_OFF);
  unsigned int* flg    = (unsigned int*)(ws + FLG_OFF);
  float* out = (float*)d_out;

  k_init<<<32, 256, 0, stream>>>(bih0, bhh0, bih1, bhh1, bias, flg);
  k_packW<<<18432, 256, 0, stream>>>(Wih0, Whh0, 128, KB0, wpk0);
  k_packW<<<32768, 256, 0, stream>>>(Wih1, Whh1, 1024, KB1, wpk1);
  k_packX<<<8192, 256, 0, stream>>>(x, a0);
  k_packH<<<512, 256, 0, stream>>>(h, a0, a1);
  lstm_main<<<256, 256, 0, stream>>>(c, out, wpk0, wpk1, a0, a1, bias, flg);
}

// Round 5
// 3076.481 us; speedup vs baseline: 1.8038x; 1.8038x over previous
//
#include <hip/hip_runtime.h>
#include <stdint.h>

// ---------------- problem constants ----------------
#define TSTEPS 256
#define KB0  36      // (128+1024)/32 k-blocks, layer 0
#define KB1  64      // (1024+1024)/32 k-blocks, layer 1

// workspace layout (bytes)
#define WPK0_OFF 0ull
#define WPK1_OFF 9437184ull
#define A0_OFF   26214400ull
#define A1_OFF   63963136ull
#define BIAS_OFF 131072000ull
#define FLG_OFF  131104768ull

typedef __attribute__((ext_vector_type(8))) short bf16x8;
typedef __attribute__((ext_vector_type(4))) float f32x4;

__device__ __forceinline__ unsigned short f2bf(float x) {
  unsigned int u = __float_as_uint(x);
  u = (u + 0x7FFFu + ((u >> 16) & 1u)) >> 16;
  return (unsigned short)u;
}

// position shuffle inside a 32-k block so each lane's 8 fragment elements
// (k in {4g..4g+3} U {16+4g..16+4g+3}, g = lane>>4) are 16B-contiguous.
__device__ __forceinline__ int kpos(int k) {
  return (((k & 15) >> 2) << 3) + (((k >> 4) & 1) << 2) + (k & 3);
}
__device__ __forceinline__ int kpos4(int k) {  // k 4-aligned
  return (((k & 15) >> 2) << 3) + (((k >> 4) & 1) << 2);
}

__device__ __forceinline__ float sigm(float z) {
  return 1.0f / (1.0f + __expf(-z));
}

// per-thread relaxed poll; agent scope => sc0 sc1 load (reads coherent point)
__device__ __forceinline__ void spin1(unsigned int* p, unsigned int tgt) {
  while (__hip_atomic_load(p, __ATOMIC_RELAXED, __HIP_MEMORY_SCOPE_AGENT) < tgt)
    __builtin_amdgcn_s_sleep(4);
}

// ---------------- pre-kernels ----------------
__global__ void k_init(const float* __restrict__ bih0, const float* __restrict__ bhh0,
                       const float* __restrict__ bih1, const float* __restrict__ bhh1,
                       float* __restrict__ bias, unsigned int* __restrict__ flg) {
  int i = blockIdx.x * 256 + threadIdx.x;   // 8192 threads
  flg[i] = 0u;                              // flags0[128*32] + flags1[128*32]
  if (i < 4096) {
    bias[i]        = bih0[i] + bhh0[i];
    bias[4096 + i] = bih1[i] + bhh1[i];
  }
}

// pack [Wih | Whh] (4096 x K) -> fragment-native bf16
__global__ void k_packW(const float* __restrict__ Wih, const float* __restrict__ Whh,
                        const int Kih, const int KB, unsigned short* __restrict__ dst) {
  const int K = KB << 5;
  const int total = K << 12;                 // 4096*K
  int i = blockIdx.x * 256 + threadIdx.x;
  if (i >= total) return;
  int n = i / K, k = i - n * K;
  float w = (k < Kih) ? Wih[n * Kih + k] : Whh[n * 1024 + (k - Kih)];
  int gt = n >> 10, hcol = n & 1023;
  int wgi = hcol >> 3, j = hcol & 7;
  int nt = gt >> 1;
  int l15 = ((gt & 1) << 3) | j;             // ntile0: i|f cols, ntile1: g|o cols
  int kb = k >> 5;
  size_t idx = ((size_t)((wgi * 2 + nt) * KB + kb) << 9) + (l15 << 5) + kpos(k & 31);
  dst[idx] = f2bf(w);
}

// pack x (B,T,V) into A0(t) k=0..127 region for all t
__global__ void k_packX(const float* __restrict__ x, unsigned short* __restrict__ a0) {
  int i = blockIdx.x * 256 + threadIdx.x;    // 2,097,152 threads
  int v = i & 127, t = (i >> 7) & 255, b = i >> 15;
  a0[(size_t)t * 73728 + (size_t)(((v >> 5) << 6) + b) * 32 + kpos(v & 31)] = f2bf(x[i]);
}

// initial h: h[0] -> A0(0) k=128+hc ; h[1] -> A1(0) k=1024+hc
__global__ void k_packH(const float* __restrict__ h,
                        unsigned short* __restrict__ a0, unsigned short* __restrict__ a1) {
  int i = blockIdx.x * 256 + threadIdx.x;    // 131072 threads
  int l = i >> 16, b = (i >> 10) & 63, hc = i & 1023;
  unsigned short v = f2bf(h[i]);
  if (l == 0) {
    int k = 128 + hc;
    a0[(size_t)(((k >> 5) << 6) + b) * 32 + kpos(k & 31)] = v;
  } else {
    int k = 1024 + hc;
    a1[(size_t)(((k >> 5) << 6) + b) * 32 + kpos(k & 31)] = v;
  }
}

// ---------------- main persistent kernel ----------------
// 128 WGs/layer; WG owns 8 h-cols (32 z-cols, all 4 gates). Wave wv owns
// batch rows wv*16..+15 over FULL K (no cross-wave reduce). Gate i/f (g/o)
// cols are lane-xor-8 partners -> one shuffle. All cross-WG data moves via
// agent-scope (sc0 sc1) accesses: no wbl2/inv anywhere.
template <int LAYER>
__device__ __forceinline__ void run_layer(
    const int wg, const int tid,
    const float* __restrict__ c_in, float* __restrict__ out,
    const unsigned short* __restrict__ W,
    unsigned short* __restrict__ a0, unsigned short* __restrict__ a1,
    const float* __restrict__ bias,
    unsigned int* flags0, unsigned int* flags1,
    unsigned short* ldsw, float (*h_lds)[8]) {
  constexpr int KB = LAYER ? KB1 : KB0;
  constexpr int AELEM = KB * 2048;

  const int lane = tid & 63, wv = tid >> 6;
  const int l15 = lane & 15, lg = lane >> 4;
  const int lbo = lane * 8;                   // B fragment offset (LDS lane-linear)

  const unsigned short* Ard = LAYER ? a1 : a0;

  // ---- stage weight slice into LDS once (dest unit = lane id) ----
  {
    const unsigned short* Wg = W + (size_t)(wg * 2) * KB * 512;
    for (int i = tid; i < KB * 128; i += 256) {
      int u = i & 63;
      *(bf16x8*)(ldsw + (size_t)((((i >> 6) << 6) | ((u & 3) << 4) | (u >> 2)) * 8)) =
          *(const bf16x8*)(Wg + (size_t)i * 8);
    }
  }

  // A fragment: row = wv*16 + l15, k-group lg
  const int arowoff = (wv * 16 + l15) * 32 + lg * 8;

  // gate math (active lanes l15<8): rows brow..brow+3, h-col hc
  const int hc = wg * 8 + l15;
  const int brow = wv * 16 + lg * 4;
  float cc[4];
  float bgi = 0.f, bgf = 0.f, bgg = 0.f, bgo = 0.f;
  if (l15 < 8) {
#pragma unroll
    for (int r = 0; r < 4; ++r)
      cc[r] = c_in[LAYER * 65536 + (brow + r) * 1024 + hc];
    bgi = bias[LAYER * 4096 + 0 * 1024 + hc];
    bgf = bias[LAYER * 4096 + 1 * 1024 + hc];
    bgg = bias[LAYER * 4096 + 2 * 1024 + hc];
    bgo = bias[LAYER * 4096 + 3 * 1024 + hc];
  }

  // h-distribution mapping (tid<128): batch row db, col quad dc0
  const int db = tid >> 1;
  const int dc0 = (tid & 1) * 4;
  const int dhc = wg * 8 + dc0;

  unsigned int* myflag = (LAYER ? flags1 : flags0) + wg * 32;
  __syncthreads();  // ldsw ready

  for (int t = 0; t < TSTEPS; ++t) {
    // ---- cross-WG wait: per-thread flag spin, then one barrier ----
    if (LAYER == 0) {
      if (t && tid < 128) spin1(flags0 + tid * 32, (unsigned int)t);
    } else {
      if (tid < 128) spin1(flags0 + tid * 32, (unsigned int)(t + 1));
      else if (t)    spin1(flags1 + (tid - 128) * 32, (unsigned int)t);
    }
    __syncthreads();

    // ---- GEMM: A loads are u64 relaxed-agent atomics (sc0 sc1, compiler-
    // tracked => no spill hazard); B from LDS; 4 independent MFMA chains ----
    const unsigned long long* Ab64 =
        (const unsigned long long*)(Ard + (size_t)t * AELEM + arowoff);
    f32x4 acc[2][2];
    acc[0][0] = (f32x4){0.f, 0.f, 0.f, 0.f};
    acc[0][1] = (f32x4){0.f, 0.f, 0.f, 0.f};
    acc[1][0] = (f32x4){0.f, 0.f, 0.f, 0.f};
    acc[1][1] = (f32x4){0.f, 0.f, 0.f, 0.f};
#pragma unroll
    for (int kb = 0; kb < KB; ++kb) {
      union { unsigned long long u[2]; bf16x8 v; } a;
      a.u[0] = __hip_atomic_load(Ab64 + (size_t)kb * 512 + 0,
                                 __ATOMIC_RELAXED, __HIP_MEMORY_SCOPE_AGENT);
      a.u[1] = __hip_atomic_load(Ab64 + (size_t)kb * 512 + 1,
                                 __ATOMIC_RELAXED, __HIP_MEMORY_SCOPE_AGENT);
      bf16x8 b0 = *(const bf16x8*)(ldsw + (size_t)kb * 512 + lbo);
      bf16x8 b1 = *(const bf16x8*)(ldsw + (size_t)(KB + kb) * 512 + lbo);
      acc[0][kb & 1] =
          __builtin_amdgcn_mfma_f32_16x16x32_bf16(a.v, b0, acc[0][kb & 1], 0, 0, 0);
      acc[1][kb & 1] =
          __builtin_amdgcn_mfma_f32_16x16x32_bf16(a.v, b1, acc[1][kb & 1], 0, 0, 0);
    }
    f32x4 z0 = acc[0][0] + acc[0][1];  // cols: l15<8 gate-i, l15>=8 gate-f
    f32x4 z1 = acc[1][0] + acc[1][1];  // cols: l15<8 gate-g, l15>=8 gate-o

    // ---- xor-8 exchange: bring f (resp. o) to the i (resp. g) lanes ----
    f32x4 zf, zo;
#pragma unroll
    for (int r = 0; r < 4; ++r) {
      zf[r] = __shfl_xor(z0[r], 8, 64);
      zo[r] = __shfl_xor(z1[r], 8, 64);
    }

    // ---- gate math (f32), c in registers across all steps ----
    if (l15 < 8) {
#pragma unroll
      for (int r = 0; r < 4; ++r) {
        float iv = sigm(z0[r] + bgi);
        float fv = sigm(zf[r] + bgf);
        float gv = tanhf(z1[r] + bgg);
        float ov = sigm(zo[r] + bgo);
        cc[r] = fv * cc[r] + iv * gv;
        h_lds[brow + r][l15] = ov * tanhf(cc[r]);
      }
    }
    __syncthreads();  // h_lds tile complete

    // ---- h distribution: packed u64 relaxed-agent stores (sc0 sc1) ----
    if (tid < 128) {
      float4 hf = *(const float4*)&h_lds[db][dc0];
      unsigned long long pk =
          (unsigned long long)(((unsigned int)f2bf(hf.y) << 16) | f2bf(hf.x)) |
          ((unsigned long long)(((unsigned int)f2bf(hf.w) << 16) | f2bf(hf.z)) << 32);
      if (LAYER == 0) {
        int k = dhc;  // h0(t) -> A1(t) first half
        __hip_atomic_store(
            (unsigned long long*)(a1 + (size_t)t * 131072 +
                                  (size_t)(((k >> 5) << 6) + db) * 32 + kpos4(k)),
            pk, __ATOMIC_RELAXED, __HIP_MEMORY_SCOPE_AGENT);
        if (t < TSTEPS - 1) {
          int k2 = 128 + dhc;  // h0(t) -> A0(t+1)
          __hip_atomic_store(
              (unsigned long long*)(a0 + (size_t)(t + 1) * 73728 +
                                    (size_t)(((k2 >> 5) << 6) + db) * 32 + kpos4(k2)),
              pk, __ATOMIC_RELAXED, __HIP_MEMORY_SCOPE_AGENT);
        }
      } else {
        *(float4*)(out + ((size_t)db * 256 + t) * 1024 + dhc) = hf;  // outs f32
        if (t < TSTEPS - 1) {
          int k = 1024 + dhc;  // h1(t) -> A1(t+1) second half
          __hip_atomic_store(
              (unsigned long long*)(a1 + (size_t)(t + 1) * 131072 +
                                    (size_t)(((k >> 5) << 6) + db) * 32 + kpos4(k)),
              pk, __ATOMIC_RELAXED, __HIP_MEMORY_SCOPE_AGENT);
        }
      }
      if (t == TSTEPS - 1)  // final h_f (f32)
        *(float4*)(out + 16777216ull + (size_t)LAYER * 65536 +
                   (size_t)db * 1024 + dhc) = hf;
    }
    if (t == TSTEPS - 1 && l15 < 8) {  // final c_f (f32) from register state
#pragma unroll
      for (int r = 0; r < 4; ++r)
        out[16777216ull + 131072ull + (size_t)LAYER * 65536 +
            (size_t)(brow + r) * 1024 + hc] = cc[r];
    }

    // end barrier: each thread's sc1 stores drained (vmcnt0) before release
    __syncthreads();
    if (tid == 0)
      __hip_atomic_store(myflag, (unsigned int)(t + 1), __ATOMIC_RELAXED,
                         __HIP_MEMORY_SCOPE_AGENT);
  }
}

__global__ __launch_bounds__(256, 1) void lstm_main(
    const float* __restrict__ c_in, float* __restrict__ out,
    const unsigned short* __restrict__ wpk0, const unsigned short* __restrict__ wpk1,
    unsigned short* a0, unsigned short* a1,
    const float* __restrict__ bias, unsigned int* flg) {
  __shared__ unsigned short ldsw[KB1 * 1024];  // 131,072 B weight slice
  __shared__ float h_lds[64][8];               // 2 KB h bounce tile
  int bid = blockIdx.x, tid = threadIdx.x;
  unsigned int* flags0 = flg;
  unsigned int* flags1 = flg + 4096;
  if (bid < 128)
    run_layer<0>(bid, tid, c_in, out, wpk0, a0, a1, bias, flags0, flags1, ldsw, h_lds);
  else
    run_layer<1>(bid - 128, tid, c_in, out, wpk1, a0, a1, bias, flags0, flags1, ldsw, h_lds);
}

// ---------------- host ----------------
extern "C" void kernel_launch(void* const* d_in, const int* in_sizes, int n_in,
                              void* d_out, int out_size, void* d_ws, size_t ws_size,
                              hipStream_t stream) {
  const float* x    = (const float*)d_in[0];
  const float* h    = (const float*)d_in[1];
  const float* c    = (const float*)d_in[2];
  const float* Wih0 = (const float*)d_in[3];
  const float* Whh0 = (const float*)d_in[4];
  const float* bih0 = (const float*)d_in[5];
  const float* bhh0 = (const float*)d_in[6];
  const float* Wih1 = (const float*)d_in[7];
  const float* Whh1 = (const float*)d_in[8];
  const float* bih1 = (const float*)d_in[9];
  const float* bhh1 = (const float*)d_in[10];

  char* ws = (char*)d_ws;
  unsigned short* wpk0 = (unsigned short*)(ws + WPK0_OFF);
  unsigned short* wpk1 = (unsigned short*)(ws + WPK1_OFF);
  unsigned short* a0   = (unsigned short*)(ws + A0_OFF);
  unsigned short* a1   = (unsigned short*)(ws + A1_OFF);
  float* bias          = (float*)(ws + BIAS_OFF);
  unsigned int* flg    = (unsigned int*)(ws + FLG_OFF);
  float* out = (float*)d_out;

  k_init<<<32, 256, 0, stream>>>(bih0, bhh0, bih1, bhh1, bias, flg);
  k_packW<<<18432, 256, 0, stream>>>(Wih0, Whh0, 128, KB0, wpk0);
  k_packW<<<32768, 256, 0, stream>>>(Wih1, Whh1, 1024, KB1, wpk1);
  k_packX<<<8192, 256, 0, stream>>>(x, a0);
  k_packH<<<512, 256, 0, stream>>>(h, a0, a1);
  lstm_main<<<256, 256, 0, stream>>>(c, out, wpk0, wpk1, a0, a1, bias, flg);
}